// Round 1
// baseline (81.440 us; speedup 1.0000x reference)
//
#include <hip/hip_runtime.h>

// DeepPoly ReLU bound propagation — pure elementwise, HBM-bound.
// 3 f32 in, 3 f32 out, N = 16.7M. One fused pass, float4 vectorized,
// grid-stride with capped grid (Guideline 11).

__device__ __forceinline__ void deeppoly_relu_one(float xf, float lf, float uf,
                                                  float& xo, float& lo_o, float& up_o) {
    xo = fmaxf(xf, 0.0f);
    const bool neg = (uf <= 0.0f);   // fully inactive
    const bool pos = (lf >= 0.0f);   // fully active (checked after neg)
    if (neg) {
        lo_o = 0.0f;
        up_o = 0.0f;
    } else if (pos) {
        lo_o = uf;
        up_o = uf;
    } else {
        // crossing: slope = u/(u-l); lower_out = l (alpha=1), upper_out = slope*u
        lo_o = lf;
        up_o = (uf / (uf - lf)) * uf;
    }
}

__global__ void __launch_bounds__(256) deeppoly_relu_kernel(
    const float4* __restrict__ x,
    const float4* __restrict__ lo,
    const float4* __restrict__ up,
    float4* __restrict__ x_out,
    float4* __restrict__ lo_out,
    float4* __restrict__ up_out,
    int n4)
{
    const int stride = gridDim.x * blockDim.x;
    for (int i = blockIdx.x * blockDim.x + threadIdx.x; i < n4; i += stride) {
        const float4 xv = x[i];
        const float4 lv = lo[i];
        const float4 uv = up[i];
        float4 xo, lv_o, uv_o;

        deeppoly_relu_one(xv.x, lv.x, uv.x, xo.x, lv_o.x, uv_o.x);
        deeppoly_relu_one(xv.y, lv.y, uv.y, xo.y, lv_o.y, uv_o.y);
        deeppoly_relu_one(xv.z, lv.z, uv.z, xo.z, lv_o.z, uv_o.z);
        deeppoly_relu_one(xv.w, lv.w, uv.w, xo.w, lv_o.w, uv_o.w);

        x_out[i]  = xo;
        lo_out[i] = lv_o;
        up_out[i] = uv_o;
    }
}

// Scalar tail (N not divisible by 4 — not expected here, but cheap insurance).
__global__ void deeppoly_relu_tail(
    const float* __restrict__ x,
    const float* __restrict__ lo,
    const float* __restrict__ up,
    float* __restrict__ x_out,
    float* __restrict__ lo_out,
    float* __restrict__ up_out,
    int start, int n)
{
    int i = start + blockIdx.x * blockDim.x + threadIdx.x;
    if (i < n) {
        deeppoly_relu_one(x[i], lo[i], up[i], x_out[i], lo_out[i], up_out[i]);
    }
}

extern "C" void kernel_launch(void* const* d_in, const int* in_sizes, int n_in,
                              void* d_out, int out_size, void* d_ws, size_t ws_size,
                              hipStream_t stream) {
    const float* x  = (const float*)d_in[0];
    const float* lo = (const float*)d_in[1];
    const float* up = (const float*)d_in[2];
    float* out = (float*)d_out;

    const int n = in_sizes[0];
    float* x_out  = out;
    float* lo_out = out + (size_t)n;
    float* up_out = out + 2 * (size_t)n;

    const int n4 = n / 4;
    const int block = 256;
    int grid = (n4 + block - 1) / block;
    if (grid > 2048) grid = 2048;
    if (grid > 0) {
        deeppoly_relu_kernel<<<grid, block, 0, stream>>>(
            (const float4*)x, (const float4*)lo, (const float4*)up,
            (float4*)x_out, (float4*)lo_out, (float4*)up_out, n4);
    }

    const int tail_start = n4 * 4;
    const int tail = n - tail_start;
    if (tail > 0) {
        deeppoly_relu_tail<<<(tail + 255) / 256, 256, 0, stream>>>(
            x, lo, up, x_out, lo_out, up_out, tail_start, n);
    }
}